// Round 12
// baseline (448.815 us; speedup 1.0000x reference)
//
#include <hip/hip_runtime.h>
#include <hip/hip_bf16.h>
#include <stdint.h>

typedef short short8 __attribute__((ext_vector_type(8)));
typedef float f32x4 __attribute__((ext_vector_type(4)));

#define EPS_Z 1e-6f

__device__ __forceinline__ unsigned short f2bf(float f) {
  uint32_t b = __float_as_uint(f);
  b += 0x7FFFu + ((b >> 16) & 1u);   // RNE
  return (unsigned short)(b >> 16);
}
__device__ __forceinline__ float bf2f(unsigned short u) {
  return __uint_as_float(((uint32_t)u) << 16);
}

__device__ __forceinline__ void gl16(const unsigned short* g, unsigned short* l) {
  __builtin_amdgcn_global_load_lds(
      (const __attribute__((address_space(1))) unsigned int*)g,
      (__attribute__((address_space(3))) unsigned int*)l, 16, 0, 0);
}

// ---------------- P: fused fp32 -> bf16 convert for x, Wk, Wq ----------------
__global__ __launch_bounds__(256) void k_cvt_all(
    const float* __restrict__ x, const float* __restrict__ Wk,
    const float* __restrict__ Wq, unsigned short* __restrict__ xbf,
    unsigned short* __restrict__ Wkbf, unsigned short* __restrict__ Wqbf) {
  const int bid = blockIdx.x;
  const float* in;
  unsigned short* out;
  int base;
  if (bid < 24576)      { in = x;  out = xbf;  base = bid; }
  else if (bid < 24864) { in = Wk; out = Wkbf; base = bid - 24576; }
  else                  { in = Wq; out = Wqbf; base = bid - 24864; }
  const int i = (base * 256 + threadIdx.x) * 8;
  float4 a = *(const float4*)(in + i);
  float4 b = *(const float4*)(in + i + 4);
  union { unsigned short u[8]; short8 v; } r;
  r.u[0] = f2bf(a.x); r.u[1] = f2bf(a.y); r.u[2] = f2bf(a.z); r.u[3] = f2bf(a.w);
  r.u[4] = f2bf(b.x); r.u[5] = f2bf(b.y); r.u[6] = f2bf(b.z); r.u[7] = f2bf(b.w);
  *(short8*)(out + i) = r.v;
}

// ---------------- A: fused q+k projection, BN=256 wide-block variant ---------
// Block = 128 rows x 256 cols (k AND q): 1024 thr / 16 waves. Waves 0-7 -> k
// (2 row-bands x 4 col-bands of 64x64), waves 8-15 -> q. Per K-tile stage:
// A 16KB + Bk 32KB + Bq 32KB = 80KB for a 128x256x2 output -- 17% less staged
// bytes/FLOP than R10's 48KB per 128x128x2, and x re-read 3x not 6x.
// LDS exactly 80KB (epilogue rowf/kcol ALIAS the dead A/Bk tiles) -> 2
// blocks/CU = 32 waves/CU (max occupancy; R10 measured ~14). Occupancy IS the
// pipeline in this 2-barrier family (R7/R8/R11 explicit variants all lost).
// Per-wave addressing/epilogue carried verbatim from R10 (R3-verified swizzle:
// 16B-chunk ^= row&7, conflict-free).
__global__ __launch_bounds__(1024, 4) void k_projqk(
    const unsigned short* __restrict__ xbf,   // [65536][768] bf16
    const unsigned short* __restrict__ Wkbf,  // [768][768] bf16
    const unsigned short* __restrict__ Wqbf,  // [768][768] bf16
    const float* __restrict__ bk,
    const float* __restrict__ bq,
    const float* __restrict__ mask,           // [128][512]
    float* __restrict__ kd,                   // [128][512][12]
    float* __restrict__ ksum_part,            // [128][4][768]
    unsigned short* __restrict__ qbf)         // [128][12][512][64]
{
  __shared__ unsigned short Ab[128][64];    // 16KB
  __shared__ unsigned short Bkb[256][64];   // 32KB
  __shared__ unsigned short Bqb[256][64];   // 32KB  -> total exactly 80KB
  float* rowf = (float*)&Ab[0][0];          // [128]   (aliases dead A tile)
  float* kcol = (float*)&Bkb[0][0];         // [2][256] (aliases dead Bk tile)

  const int tid = threadIdx.x;    // 0..1023
  const int lane = tid & 63;
  const int wid = tid >> 6;       // 0..15
  const int isQ = wid >> 3;       // 0: k-waves (0-7), 1: q-waves (8-15)
  const int w3 = wid & 7;
  const int wr = w3 >> 2;         // 0..1 (64-row band)
  const int wc = w3 & 3;          // 0..3 (64-col band)
  const int colTile = blockIdx.x;   // 0..2
  const int rowTile = blockIdx.y;   // 0..511
  const int bm = rowTile >> 2;
  const int trow = rowTile & 3;
  const size_t rowBase = (size_t)rowTile * 128;
  const int colBase = colTile * 256;
  const int lrow = lane & 15;
  const int lgrp = lane >> 4;

  f32x4 acc[4][4] = {};

  for (int kt = 0; kt < 12; ++kt) {
    const int k0 = kt * 64;
    __syncthreads();
    {
      // A: 1024 16B-chunks, 1/thread
      const int r = tid >> 3;
      const int scc = (tid & 7) ^ (r & 7);   // inverse-swizzled source col
      gl16(xbf + (rowBase + r) * 768 + k0 + scc * 8, &Ab[0][0] + tid * 8);
      // Bk, Bq: 2048 chunks each, 2/thread
#pragma unroll
      for (int c = 0; c < 2; ++c) {
        const int chunk = c * 1024 + tid;
        const int rb = chunk >> 3;
        const int sccb = (chunk & 7) ^ (rb & 7);
        gl16(Wkbf + (size_t)(colBase + rb) * 768 + k0 + sccb * 8,
             &Bkb[0][0] + chunk * 8);
        gl16(Wqbf + (size_t)(colBase + rb) * 768 + k0 + sccb * 8,
             &Bqb[0][0] + chunk * 8);
      }
    }
    __syncthreads();
    const unsigned short* Bsel = isQ ? &Bqb[0][0] : &Bkb[0][0];
#pragma unroll
    for (int kk = 0; kk < 64; kk += 32) {
      short8 av[4], bv4[4];
#pragma unroll
      for (int rf = 0; rf < 4; ++rf) {
        const int row = wr * 64 + rf * 16 + lrow;
        const int cidx = ((kk >> 3) + lgrp) ^ (row & 7);   // swizzled read
        av[rf] = *(const short8*)&Ab[row][cidx * 8];
      }
#pragma unroll
      for (int cf = 0; cf < 4; ++cf) {
        const int row = wc * 64 + cf * 16 + lrow;
        const int cidx = ((kk >> 3) + lgrp) ^ (row & 7);
        bv4[cf] = *(const short8*)(Bsel + row * 64 + cidx * 8);
      }
#pragma unroll
      for (int rf = 0; rf < 4; ++rf)
#pragma unroll
        for (int cf = 0; cf < 4; ++cf)
          acc[rf][cf] = __builtin_amdgcn_mfma_f32_16x16x32_bf16(
              av[rf], bv4[cf], acc[rf][cf], 0, 0, 0);
    }
  }

  // ---- epilogue: tiles are dead; alias rowf/kcol onto them ----
  __syncthreads();                       // all waves done reading LDS tiles
  if (tid < 128) rowf[tid] = mask[bm * 512 + trow * 128 + tid];
  __syncthreads();                       // rowf visible

  const float* bias = isQ ? bq : bk;
  float bvv[4];
#pragma unroll
  for (int cf = 0; cf < 4; ++cf)
    bvv[cf] = bias[colBase + wc * 64 + cf * 16 + lrow];
#pragma unroll
  for (int rf = 0; rf < 4; ++rf)
#pragma unroll
    for (int cf = 0; cf < 4; ++cf)
#pragma unroll
      for (int j = 0; j < 4; ++j) {
        float v = acc[rf][cf][j] + bvv[cf];
        v = (v > 0.0f) ? (v + 1.0f) : __expf(v);
        if (!isQ) v *= rowf[wr * 64 + rf * 16 + lgrp * 4 + j];
        acc[rf][cf][j] = v;
      }

  const int head = colTile * 4 + wc;   // each wave-column covers one head

  if (!isQ) {
    // kd[t][head]: row-sums over the head's 64 cols
#pragma unroll
    for (int rf = 0; rf < 4; ++rf)
#pragma unroll
      for (int j = 0; j < 4; ++j) {
        float s = acc[rf][0][j] + acc[rf][1][j] + acc[rf][2][j] + acc[rf][3][j];
        s += __shfl_xor(s, 1, 64);
        s += __shfl_xor(s, 2, 64);
        s += __shfl_xor(s, 4, 64);
        s += __shfl_xor(s, 8, 64);
        if ((lane & 15) == 0) {
          const int t = trow * 128 + wr * 64 + rf * 16 + lgrp * 4 + j;
          kd[((size_t)bm * 512 + t) * 12 + head] = s;
        }
      }
    // ksum column partials (over this 128-row tile)
#pragma unroll
    for (int cf = 0; cf < 4; ++cf) {
      float s = 0.f;
#pragma unroll
      for (int rf = 0; rf < 4; ++rf)
#pragma unroll
        for (int j = 0; j < 4; ++j) s += acc[rf][cf][j];
      s += __shfl_xor(s, 16, 64);
      s += __shfl_xor(s, 32, 64);
      if (lane < 16) kcol[wr * 256 + wc * 64 + cf * 16 + lane] = s;
    }
  } else {
    // store activated q as bf16: qbf[bm][head][t][d]
#pragma unroll
    for (int rf = 0; rf < 4; ++rf)
#pragma unroll
      for (int j = 0; j < 4; ++j) {
        const int t = trow * 128 + wr * 64 + rf * 16 + lgrp * 4 + j;
        unsigned short* qp = qbf + (((size_t)bm * 12 + head) * 512 + t) * 64 + lrow;
#pragma unroll
        for (int cf = 0; cf < 4; ++cf)
          qp[cf * 16] = f2bf(acc[rf][cf][j]);
      }
  }

  __syncthreads();
  if (tid < 256)
    ksum_part[((size_t)bm * 4 + trow) * 768 + colBase + tid] =
        kcol[tid] + kcol[256 + tid];
}

// ---------------- C+Z fused launch ----------------
// blocks 0..511:   xk_part[bm][ts][n][c] = sum_{t in slice} kd[t][n]*x[t][c]
// blocks 512..1023: Z[bm][n][t] = 1/(q . ksum + eps)
__global__ __launch_bounds__(256) void k_xkz(const unsigned short* __restrict__ xbf,
                                             const float* __restrict__ kd,
                                             float* __restrict__ xk_part,
                                             const unsigned short* __restrict__ qbf,
                                             const float* __restrict__ ksum_part,
                                             float* __restrict__ Z) {
  const int bid = blockIdx.x, tid = threadIdx.x;
  if (bid < 512) {
    __shared__ float kdl[128][12];
    const int bm = bid >> 2, ts = bid & 3;
    for (int i = tid; i < 128 * 12; i += 256)
      kdl[i / 12][i % 12] = kd[((size_t)bm * 512 + ts * 128 + i / 12) * 12 + (i % 12)];
    __syncthreads();
    if (tid < 192) {
      float a[12][4];
#pragma unroll
      for (int n = 0; n < 12; ++n)
#pragma unroll
        for (int j = 0; j < 4; ++j) a[n][j] = 0.f;
      const int c = tid * 4;
      const unsigned short* xp = xbf + ((size_t)bm * 512 + ts * 128) * 768 + c;
      for (int t = 0; t < 128; ++t) {
        ushort4 xv = *(const ushort4*)(xp + (size_t)t * 768);
        const float x0 = bf2f(xv.x), x1 = bf2f(xv.y), x2 = bf2f(xv.z), x3 = bf2f(xv.w);
#pragma unroll
        for (int n = 0; n < 12; ++n) {
          const float kv = kdl[t][n];
          a[n][0] += kv * x0; a[n][1] += kv * x1; a[n][2] += kv * x2; a[n][3] += kv * x3;
        }
      }
      float* op = xk_part + ((size_t)bm * 4 + ts) * 12 * 768 + c;
#pragma unroll
      for (int n = 0; n < 12; ++n)
        *(float4*)(op + (size_t)n * 768) = make_float4(a[n][0], a[n][1], a[n][2], a[n][3]);
    }
  } else {
    __shared__ float ksum_l[768];
    const int b2 = bid - 512;
    const int bm = b2 >> 2, ts = b2 & 3;
    for (int i = tid; i < 768; i += 256) {
      const float* kp = ksum_part + (size_t)bm * 3072 + i;
      ksum_l[i] = kp[0] + kp[768] + kp[1536] + kp[2304];
    }
    __syncthreads();
#pragma unroll
    for (int i = 0; i < 6; ++i) {
      const int task = i * 256 + tid;        // 12 n x 128 t
      const int n = task >> 7;
      const int t = ts * 128 + (task & 127);
      const unsigned short* qp = qbf + (((size_t)bm * 12 + n) * 512 + t) * 64;
      const float* kp = &ksum_l[n * 64];
      float s = 0.f;
#pragma unroll
      for (int c = 0; c < 8; ++c) {
        short8 qv = *(const short8*)(qp + c * 8);
        s += bf2f((unsigned short)qv[0]) * kp[c * 8 + 0]
           + bf2f((unsigned short)qv[1]) * kp[c * 8 + 1]
           + bf2f((unsigned short)qv[2]) * kp[c * 8 + 2]
           + bf2f((unsigned short)qv[3]) * kp[c * 8 + 3]
           + bf2f((unsigned short)qv[4]) * kp[c * 8 + 4]
           + bf2f((unsigned short)qv[5]) * kp[c * 8 + 5]
           + bf2f((unsigned short)qv[6]) * kp[c * 8 + 6]
           + bf2f((unsigned short)qv[7]) * kp[c * 8 + 7];
      }
      Z[((size_t)bm * 12 + n) * 512 + t] = 1.0f / (s + EPS_Z);
    }
  }
}

// ---------------- D: per (2-bm batch, head): S[2][64] then G -----------------
// grid (12 n, 64 bmG), 256 threads. Wv/Wp float4 loaded ONCE per output and
// used for BOTH bm (interleaved, single w live -- no register arrays).
__global__ __launch_bounds__(256) void k_sg(const float* __restrict__ ksum_part,
                                            const float* __restrict__ xk_part,
                                            const float* __restrict__ Wv,
                                            const float* __restrict__ bv,
                                            const float* __restrict__ Wp,
                                            float* __restrict__ G) {
  __shared__ __align__(16) float xk_l[2][768];
  __shared__ __align__(16) float S_l[2][64];
  __shared__ float kdsum_l[2];
  const int n = blockIdx.x, bm0 = blockIdx.y * 2, tid = threadIdx.x;

  for (int task = tid; task < 384; task += 256) {
    const int b = task / 192, c4 = task - b * 192;
    const float* xp = xk_part + (size_t)(bm0 + b) * 4 * 9216 + n * 768 + c4 * 4;
    float4 a = *(const float4*)(xp);
    float4 bb = *(const float4*)(xp + 9216);
    float4 c = *(const float4*)(xp + 18432);
    float4 d = *(const float4*)(xp + 27648);
    *(float4*)&xk_l[b][c4 * 4] = make_float4(a.x + bb.x + c.x + d.x,
                                             a.y + bb.y + c.y + d.y,
                                             a.z + bb.z + c.z + d.z,
                                             a.w + bb.w + c.w + d.w);
  }
  if (tid < 128) {
    const int b = tid >> 6, d = tid & 63;
    const float* kp = ksum_part + (size_t)(bm0 + b) * 3072 + n * 64 + d;
    float s = kp[0] + kp[768] + kp[1536] + kp[2304];
    s += __shfl_xor(s, 1, 64);
    s += __shfl_xor(s, 2, 64);
    s += __shfl_xor(s, 4, 64);
    s += __shfl_xor(s, 8, 64);
    s += __shfl_xor(s, 16, 64);
    s += __shfl_xor(s, 32, 64);
    if (d == 0) kdsum_l[b] = s;
  }
  __syncthreads();

  {
    const int e = tid >> 2, q = tid & 3;
    const float4* wv = (const float4*)(Wv + (size_t)(n * 64 + e) * 768 + q * 192);
    const float4* x0 = (const float4*)(&xk_l[0][0] + q * 192);
    const float4* x1 = (const float4*)(&xk_l[1][0] + q * 192);
    float s0 = 0.f, s1 = 0.f;
#pragma unroll
    for (int i = 0; i < 48; ++i) {
      float4 w = wv[i];
      float4 a = x0[i], b = x1[i];
      s0 += w.x * a.x + w.y * a.y + w.z * a.z + w.w * a.w;
      s1 += w.x * b.x + w.y * b.y + w.z * b.z + w.w * b.w;
    }
    s0 += __shfl_xor(s0, 1, 64);
    s0 += __shfl_xor(s0, 2, 64);
    s1 += __shfl_xor(s1, 1, 64);
    s1 += __shfl_xor(s1, 2, 64);
    if (q == 0) {
      const float bve = bv[n * 64 + e];
      S_l[0][e] = s0 + bve * kdsum_l[0];
      S_l[1][e] = s1 + bve * kdsum_l[1];
    }
  }
  __syncthreads();

#pragma unroll
  for (int r = 0; r < 3; ++r) {
    const int p = r * 256 + tid;
    const float4* wp = (const float4*)(Wp + (size_t)p * 768 + n * 64);
    const float4* s0p = (const float4*)&S_l[0][0];
    const float4* s1p = (const float4*)&S_l[1][0];
    float g0 = 0.f, g1 = 0.f;
#pragma unroll
    for (int i = 0; i < 16; ++i) {
      float4 w = wp[i];
      float4 a = s0p[i], b = s1p[i];
      g0 += w.x * a.x + w.y * a.y + w.z * a.z + w.w * a.w;
      g1 += w.x * b.x + w.y * b.y + w.z * b.z + w.w * b.w;
    }
    G[((size_t)(bm0 + 0) * 12 + n) * 768 + p] = g0;
    G[((size_t)(bm0 + 1) * 12 + n) * 768 + p] = g1;
  }
}

// ---------------- F: out[t][p] = bp[p] + sum_n Z[n][t]*G[n][p] ----------------
__global__ __launch_bounds__(256) void k_out(const float* __restrict__ Z,
                                             const float* __restrict__ G,
                                             const float* __restrict__ bp,
                                             float* __restrict__ outp) {
  __shared__ __align__(16) float G_l[9216];
  __shared__ float Z_l[768];
  __shared__ __align__(16) float bp_l[768];
  const int bm = blockIdx.x;
  const int tbase = blockIdx.y * 64;
  const int tid = threadIdx.x;
  for (int i = tid; i < 9216; i += 256) G_l[i] = G[(size_t)bm * 9216 + i];
  for (int i = tid; i < 768; i += 256) {
    bp_l[i] = bp[i];
    Z_l[i] = Z[((size_t)bm * 12 + (i >> 6)) * 512 + tbase + (i & 63)];
  }
  __syncthreads();
  for (int it = 0; it < 48; ++it) {
    const int idx = it * 1024 + tid * 4;
    const int t = idx / 768;
    const int p = idx - t * 768;
    float4 o = *(const float4*)&bp_l[p];
#pragma unroll
    for (int n = 0; n < 12; ++n) {
      const float z = Z_l[n * 64 + t];
      const float4 g = *(const float4*)&G_l[n * 768 + p];
      o.x += z * g.x; o.y += z * g.y; o.z += z * g.z; o.w += z * g.w;
    }
    *(float4*)&outp[((size_t)bm * 512 + tbase + t) * 768 + p] = o;
  }
}

extern "C" void kernel_launch(void* const* d_in, const int* in_sizes, int n_in,
                              void* d_out, int out_size, void* d_ws, size_t ws_size,
                              hipStream_t stream) {
  const float* x    = (const float*)d_in[0];
  const float* mask = (const float*)d_in[1];
  const float* Wq   = (const float*)d_in[2];
  const float* bq   = (const float*)d_in[3];
  const float* Wk   = (const float*)d_in[4];
  const float* bk   = (const float*)d_in[5];
  const float* Wv   = (const float*)d_in[6];
  const float* bv   = (const float*)d_in[7];
  const float* Wp   = (const float*)d_in[8];
  const float* bp   = (const float*)d_in[9];
  float* outp = (float*)d_out;

  char* ws = (char*)d_ws;
  unsigned short* xbf  = (unsigned short*)(ws);                  // 100,663,296 B
  unsigned short* Wkbf = (unsigned short*)(ws + 100663296);      //   1,179,648
  unsigned short* Wqbf = (unsigned short*)(ws + 101842944);      //   1,179,648
  float* kd        = (float*)(ws + 103022592);                   //   3,145,728
  float* ksum_part = (float*)(ws + 106168320);                   //   1,572,864 ([128][4][768])
  float* xk_part   = (float*)(ws + 107741184);                   //  18,874,368
  float* Zb        = (float*)(ws + 126615552);                   //   3,145,728
  float* G         = (float*)(ws + 129761280);                   //   4,718,592
  // total ws: 134,479,872 B
  // q (bf16, 100,663,296 B) lives in d_out's first half until k_out overwrites.
  unsigned short* qbf = (unsigned short*)d_out;

  hipLaunchKernelGGL(k_cvt_all, dim3(25152), dim3(256), 0, stream,
                     x, Wk, Wq, xbf, Wkbf, Wqbf);
  hipLaunchKernelGGL(k_projqk, dim3(3, 512), dim3(1024), 0, stream,
                     xbf, Wkbf, Wqbf, bk, bq, mask, kd, ksum_part, qbf);
  hipLaunchKernelGGL(k_xkz, dim3(1024), dim3(256), 0, stream,
                     xbf, kd, xk_part, qbf, ksum_part, Zb);
  hipLaunchKernelGGL(k_sg, dim3(12, 64), dim3(256), 0, stream,
                     ksum_part, xk_part, Wv, bv, Wp, G);
  hipLaunchKernelGGL(k_out, dim3(128, 8), dim3(256), 0, stream, Zb, G, bp, outp);
}

// Round 13
// 403.804 us; speedup vs baseline: 1.1115x; 1.1115x over previous
//
#include <hip/hip_runtime.h>
#include <hip/hip_bf16.h>
#include <stdint.h>

typedef short short8 __attribute__((ext_vector_type(8)));
typedef float f32x4 __attribute__((ext_vector_type(4)));

#define EPS_Z 1e-6f

__device__ __forceinline__ unsigned short f2bf(float f) {
  uint32_t b = __float_as_uint(f);
  b += 0x7FFFu + ((b >> 16) & 1u);   // RNE
  return (unsigned short)(b >> 16);
}
__device__ __forceinline__ float bf2f(unsigned short u) {
  return __uint_as_float(((uint32_t)u) << 16);
}

__device__ __forceinline__ void gl16(const unsigned short* g, unsigned short* l) {
  __builtin_amdgcn_global_load_lds(
      (const __attribute__((address_space(1))) unsigned int*)g,
      (__attribute__((address_space(3))) unsigned int*)l, 16, 0, 0);
}

// ---------------- P: fused fp32 -> bf16 convert for x, Wk, Wq ----------------
__global__ __launch_bounds__(256) void k_cvt_all(
    const float* __restrict__ x, const float* __restrict__ Wk,
    const float* __restrict__ Wq, unsigned short* __restrict__ xbf,
    unsigned short* __restrict__ Wkbf, unsigned short* __restrict__ Wqbf) {
  const int bid = blockIdx.x;
  const float* in;
  unsigned short* out;
  int base;
  if (bid < 24576)      { in = x;  out = xbf;  base = bid; }
  else if (bid < 24864) { in = Wk; out = Wkbf; base = bid - 24576; }
  else                  { in = Wq; out = Wqbf; base = bid - 24864; }
  const int i = (base * 256 + threadIdx.x) * 8;
  float4 a = *(const float4*)(in + i);
  float4 b = *(const float4*)(in + i + 4);
  union { unsigned short u[8]; short8 v; } r;
  r.u[0] = f2bf(a.x); r.u[1] = f2bf(a.y); r.u[2] = f2bf(a.z); r.u[3] = f2bf(a.w);
  r.u[4] = f2bf(b.x); r.u[5] = f2bf(b.y); r.u[6] = f2bf(b.z); r.u[7] = f2bf(b.w);
  *(short8*)(out + i) = r.v;
}

// ---------------- A: fused q+k projection GEMM (R10-proven config) -----------
// 512 thr / 8 waves: waves 0-3 compute the k-tile, waves 4-7 the q-tile; each
// wave one 64x64 quadrant. x staged ONCE for both GEMMs. Single-buffered LDS
// (50.7KB -> 3 blocks/CU, ~24 waves): occupancy IS the pipeline (m114).
// Challengers that all regressed: dual-256thr (213), 256-row dbuf (215),
// counted vmcnt (313), BK=32 2-phase (215), BN=256 wide (236). Keep this.
// Grid dim3(6,512) colTile-fastest (R5/R10-proven 192us; flat XCD swizzle
// was -18us WORSE -- kernel is L3-fed, not HBM-bound).
// LDS XOR-swizzle (16B-chunk ^= row&7): conflict-free (R3-verified, SQ=0).
__global__ __launch_bounds__(512, 2) void k_projqk(
    const unsigned short* __restrict__ xbf,   // [65536][768] bf16
    const unsigned short* __restrict__ Wkbf,  // [768][768] bf16
    const unsigned short* __restrict__ Wqbf,  // [768][768] bf16
    const float* __restrict__ bk,
    const float* __restrict__ bq,
    const float* __restrict__ mask,           // [128][512]
    float* __restrict__ kd,                   // [128][512][12]
    float* __restrict__ ksum_part,            // [128][4][768]
    unsigned short* __restrict__ qbf)         // [128][12][512][64]
{
  __shared__ unsigned short Ab[128][64];    // 16KB
  __shared__ unsigned short Bkb[128][64];   // 16KB
  __shared__ unsigned short Bqb[128][64];   // 16KB
  __shared__ float rowf[128];
  __shared__ float kcol[2][128];

  const int tid = threadIdx.x;    // 0..511
  const int lane = tid & 63;
  const int wid = tid >> 6;       // 0..7
  const int isQ = wid >> 2;       // 0: k-waves, 1: q-waves
  const int w2 = wid & 3;
  const int wr = w2 >> 1, wc = w2 & 1;
  const int colTile = blockIdx.x;   // 0..5
  const int rowTile = blockIdx.y;   // 0..511
  const int bm = rowTile >> 2;
  const int trow = rowTile & 3;
  const size_t rowBase = (size_t)rowTile * 128;
  const int colBase = colTile * 128;
  const int lrow = lane & 15;
  const int lgrp = lane >> 4;

  if (tid < 128) rowf[tid] = mask[bm * 512 + trow * 128 + tid];

  f32x4 acc[4][4] = {};

  for (int kt = 0; kt < 12; ++kt) {
    const int k0 = kt * 64;
    __syncthreads();
#pragma unroll
    for (int c = 0; c < 2; ++c) {
      const int chunk = c * 512 + tid;           // 16B-slot index 0..1023
      const int r = chunk >> 3;                  // local row 0..127
      const int cc = chunk & 7;
      const int scc = cc ^ (r & 7);              // inverse-swizzled source col
      const int ldst = c * 4096 + wid * 512;     // wave-uniform dest (shorts)
      gl16(xbf + (rowBase + r) * 768 + k0 + scc * 8, &Ab[0][0] + ldst);
      gl16(Wkbf + (size_t)(colBase + r) * 768 + k0 + scc * 8, &Bkb[0][0] + ldst);
      gl16(Wqbf + (size_t)(colBase + r) * 768 + k0 + scc * 8, &Bqb[0][0] + ldst);
    }
    __syncthreads();
    const unsigned short* Bsel = isQ ? &Bqb[0][0] : &Bkb[0][0];
#pragma unroll
    for (int kk = 0; kk < 64; kk += 32) {
      short8 av[4], bv4[4];
#pragma unroll
      for (int rf = 0; rf < 4; ++rf) {
        const int row = wr * 64 + rf * 16 + lrow;
        const int cidx = ((kk >> 3) + lgrp) ^ (row & 7);
        av[rf] = *(const short8*)&Ab[row][cidx * 8];
      }
#pragma unroll
      for (int cf = 0; cf < 4; ++cf) {
        const int row = wc * 64 + cf * 16 + lrow;
        const int cidx = ((kk >> 3) + lgrp) ^ (row & 7);
        bv4[cf] = *(const short8*)(Bsel + row * 64 + cidx * 8);
      }
#pragma unroll
      for (int rf = 0; rf < 4; ++rf)
#pragma unroll
        for (int cf = 0; cf < 4; ++cf)
          acc[rf][cf] = __builtin_amdgcn_mfma_f32_16x16x32_bf16(
              av[rf], bv4[cf], acc[rf][cf], 0, 0, 0);
    }
  }

  // epilogue: bias + elu+1 (+mask for k-waves)
  const float* bias = isQ ? bq : bk;
  float bvv[4];
#pragma unroll
  for (int cf = 0; cf < 4; ++cf)
    bvv[cf] = bias[colBase + wc * 64 + cf * 16 + lrow];
#pragma unroll
  for (int rf = 0; rf < 4; ++rf)
#pragma unroll
    for (int cf = 0; cf < 4; ++cf)
#pragma unroll
      for (int j = 0; j < 4; ++j) {
        float v = acc[rf][cf][j] + bvv[cf];
        v = (v > 0.0f) ? (v + 1.0f) : __expf(v);
        if (!isQ) v *= rowf[wr * 64 + rf * 16 + lgrp * 4 + j];
        acc[rf][cf][j] = v;
      }

  const int head = colTile * 2 + wc;   // each wave-column covers one head

  if (!isQ) {
    // kd[t][head] row-sums over the head's 64 cols
#pragma unroll
    for (int rf = 0; rf < 4; ++rf)
#pragma unroll
      for (int j = 0; j < 4; ++j) {
        float s = acc[rf][0][j] + acc[rf][1][j] + acc[rf][2][j] + acc[rf][3][j];
        s += __shfl_xor(s, 1, 64);
        s += __shfl_xor(s, 2, 64);
        s += __shfl_xor(s, 4, 64);
        s += __shfl_xor(s, 8, 64);
        if ((lane & 15) == 0) {
          const int t = trow * 128 + wr * 64 + rf * 16 + lgrp * 4 + j;
          kd[((size_t)bm * 512 + t) * 12 + head] = s;
        }
      }
    // column sums (ksum partial over this 128-row tile)
#pragma unroll
    for (int cf = 0; cf < 4; ++cf) {
      float s = 0.f;
#pragma unroll
      for (int rf = 0; rf < 4; ++rf)
#pragma unroll
        for (int j = 0; j < 4; ++j) s += acc[rf][cf][j];
      s += __shfl_xor(s, 16, 64);
      s += __shfl_xor(s, 32, 64);
      if (lane < 16) kcol[wr][wc * 64 + cf * 16 + lane] = s;
    }
  } else {
    // store activated q as bf16: qbf[bm][head][t][d]
#pragma unroll
    for (int rf = 0; rf < 4; ++rf)
#pragma unroll
      for (int j = 0; j < 4; ++j) {
        const int t = trow * 128 + wr * 64 + rf * 16 + lgrp * 4 + j;
        unsigned short* qp = qbf + (((size_t)bm * 12 + head) * 512 + t) * 64 + lrow;
#pragma unroll
        for (int cf = 0; cf < 4; ++cf)
          qp[cf * 16] = f2bf(acc[rf][cf][j]);
      }
  }

  __syncthreads();
  if (tid < 128)
    ksum_part[((size_t)bm * 4 + trow) * 768 + colBase + tid] =
        kcol[0][tid] + kcol[1][tid];
}

// ---------------- C+Z fused launch ----------------
// blocks 0..511:   xk_part[bm][ts][n][c] = sum_{t in slice} kd[t][n]*x[t][c]
// blocks 512..1023: Z[bm][n][t] = 1/(q . ksum + eps)
__global__ __launch_bounds__(256) void k_xkz(const unsigned short* __restrict__ xbf,
                                             const float* __restrict__ kd,
                                             float* __restrict__ xk_part,
                                             const unsigned short* __restrict__ qbf,
                                             const float* __restrict__ ksum_part,
                                             float* __restrict__ Z) {
  const int bid = blockIdx.x, tid = threadIdx.x;
  if (bid < 512) {
    __shared__ float kdl[128][12];
    const int bm = bid >> 2, ts = bid & 3;
    for (int i = tid; i < 128 * 12; i += 256)
      kdl[i / 12][i % 12] = kd[((size_t)bm * 512 + ts * 128 + i / 12) * 12 + (i % 12)];
    __syncthreads();
    if (tid < 192) {
      float a[12][4];
#pragma unroll
      for (int n = 0; n < 12; ++n)
#pragma unroll
        for (int j = 0; j < 4; ++j) a[n][j] = 0.f;
      const int c = tid * 4;
      const unsigned short* xp = xbf + ((size_t)bm * 512 + ts * 128) * 768 + c;
      for (int t = 0; t < 128; ++t) {
        ushort4 xv = *(const ushort4*)(xp + (size_t)t * 768);
        const float x0 = bf2f(xv.x), x1 = bf2f(xv.y), x2 = bf2f(xv.z), x3 = bf2f(xv.w);
#pragma unroll
        for (int n = 0; n < 12; ++n) {
          const float kv = kdl[t][n];
          a[n][0] += kv * x0; a[n][1] += kv * x1; a[n][2] += kv * x2; a[n][3] += kv * x3;
        }
      }
      float* op = xk_part + ((size_t)bm * 4 + ts) * 12 * 768 + c;
#pragma unroll
      for (int n = 0; n < 12; ++n)
        *(float4*)(op + (size_t)n * 768) = make_float4(a[n][0], a[n][1], a[n][2], a[n][3]);
    }
  } else {
    __shared__ float ksum_l[768];
    const int b2 = bid - 512;
    const int bm = b2 >> 2, ts = b2 & 3;
    for (int i = tid; i < 768; i += 256) {
      const float* kp = ksum_part + (size_t)bm * 3072 + i;
      ksum_l[i] = kp[0] + kp[768] + kp[1536] + kp[2304];
    }
    __syncthreads();
#pragma unroll
    for (int i = 0; i < 6; ++i) {
      const int task = i * 256 + tid;        // 12 n x 128 t
      const int n = task >> 7;
      const int t = ts * 128 + (task & 127);
      const unsigned short* qp = qbf + (((size_t)bm * 12 + n) * 512 + t) * 64;
      const float* kp = &ksum_l[n * 64];
      float s = 0.f;
#pragma unroll
      for (int c = 0; c < 8; ++c) {
        short8 qv = *(const short8*)(qp + c * 8);
        s += bf2f((unsigned short)qv[0]) * kp[c * 8 + 0]
           + bf2f((unsigned short)qv[1]) * kp[c * 8 + 1]
           + bf2f((unsigned short)qv[2]) * kp[c * 8 + 2]
           + bf2f((unsigned short)qv[3]) * kp[c * 8 + 3]
           + bf2f((unsigned short)qv[4]) * kp[c * 8 + 4]
           + bf2f((unsigned short)qv[5]) * kp[c * 8 + 5]
           + bf2f((unsigned short)qv[6]) * kp[c * 8 + 6]
           + bf2f((unsigned short)qv[7]) * kp[c * 8 + 7];
      }
      Z[((size_t)bm * 12 + n) * 512 + t] = 1.0f / (s + EPS_Z);
    }
  }
}

// ---------------- D: per (4-bm batch, head): S[4][64] then G -----------------
// grid (12 n, 32 bmG), 256 threads. Wv/Wp float4 loaded ONCE per output and
// used for FOUR bm (interleaved scalar accumulators s0..s3 / g0..g3 -- single
// w live, no register arrays, rule-20-safe). Weight stream 301 -> 150 MB vs
// the R10 2-bm version.
__global__ __launch_bounds__(256) void k_sg(const float* __restrict__ ksum_part,
                                            const float* __restrict__ xk_part,
                                            const float* __restrict__ Wv,
                                            const float* __restrict__ bv,
                                            const float* __restrict__ Wp,
                                            float* __restrict__ G) {
  __shared__ __align__(16) float xk_l[4][768];   // 12KB
  __shared__ __align__(16) float S_l[4][64];
  __shared__ float kdsum_l[4];
  const int n = blockIdx.x, bm0 = blockIdx.y * 4, tid = threadIdx.x;

  // xk[b][c] = sum of 4 t-slice partials (4 bm x 192 float4 = 768 tasks)
  for (int task = tid; task < 768; task += 256) {
    const int b = task / 192, c4 = task - b * 192;
    const float* xp = xk_part + (size_t)(bm0 + b) * 4 * 9216 + n * 768 + c4 * 4;
    float4 a0 = *(const float4*)(xp);
    float4 a1 = *(const float4*)(xp + 9216);
    float4 a2 = *(const float4*)(xp + 18432);
    float4 a3 = *(const float4*)(xp + 27648);
    *(float4*)&xk_l[b][c4 * 4] = make_float4(a0.x + a1.x + a2.x + a3.x,
                                             a0.y + a1.y + a2.y + a3.y,
                                             a0.z + a1.z + a2.z + a3.z,
                                             a0.w + a1.w + a2.w + a3.w);
  }
  {
    // kdsum[b]: wave b reduces its 64 lanes (256 thr = 4 bm x 64 d exactly)
    const int b = tid >> 6, d = tid & 63;
    const float* kp = ksum_part + (size_t)(bm0 + b) * 3072 + n * 64 + d;
    float s = kp[0] + kp[768] + kp[1536] + kp[2304];
    s += __shfl_xor(s, 1, 64);
    s += __shfl_xor(s, 2, 64);
    s += __shfl_xor(s, 4, 64);
    s += __shfl_xor(s, 8, 64);
    s += __shfl_xor(s, 16, 64);
    s += __shfl_xor(s, 32, 64);
    if (d == 0) kdsum_l[b] = s;
  }
  __syncthreads();

  // S[b][e] = xk[b] . Wv[n*64+e] + bv*kdsum[b]; 4 threads per e, w shared x4
  {
    const int e = tid >> 2, q = tid & 3;
    const float4* wv = (const float4*)(Wv + (size_t)(n * 64 + e) * 768 + q * 192);
    const float4* x0 = (const float4*)(&xk_l[0][0] + q * 192);
    const float4* x1 = (const float4*)(&xk_l[1][0] + q * 192);
    const float4* x2 = (const float4*)(&xk_l[2][0] + q * 192);
    const float4* x3 = (const float4*)(&xk_l[3][0] + q * 192);
    float s0 = 0.f, s1 = 0.f, s2 = 0.f, s3 = 0.f;
#pragma unroll
    for (int i = 0; i < 48; ++i) {
      float4 w = wv[i];
      float4 a = x0[i];
      s0 += w.x * a.x + w.y * a.y + w.z * a.z + w.w * a.w;
      float4 b = x1[i];
      s1 += w.x * b.x + w.y * b.y + w.z * b.z + w.w * b.w;
      float4 c = x2[i];
      s2 += w.x * c.x + w.y * c.y + w.z * c.z + w.w * c.w;
      float4 d = x3[i];
      s3 += w.x * d.x + w.y * d.y + w.z * d.z + w.w * d.w;
    }
    s0 += __shfl_xor(s0, 1, 64); s0 += __shfl_xor(s0, 2, 64);
    s1 += __shfl_xor(s1, 1, 64); s1 += __shfl_xor(s1, 2, 64);
    s2 += __shfl_xor(s2, 1, 64); s2 += __shfl_xor(s2, 2, 64);
    s3 += __shfl_xor(s3, 1, 64); s3 += __shfl_xor(s3, 2, 64);
    if (q == 0) {
      const float bve = bv[n * 64 + e];
      S_l[0][e] = s0 + bve * kdsum_l[0];
      S_l[1][e] = s1 + bve * kdsum_l[1];
      S_l[2][e] = s2 + bve * kdsum_l[2];
      S_l[3][e] = s3 + bve * kdsum_l[3];
    }
  }
  __syncthreads();

  // G[bm][n][p] = S[b] . Wp[p][n*64..+63]; w shared across 4 bm
#pragma unroll
  for (int r = 0; r < 3; ++r) {
    const int p = r * 256 + tid;
    const float4* wp = (const float4*)(Wp + (size_t)p * 768 + n * 64);
    const float4* s0p = (const float4*)&S_l[0][0];
    const float4* s1p = (const float4*)&S_l[1][0];
    const float4* s2p = (const float4*)&S_l[2][0];
    const float4* s3p = (const float4*)&S_l[3][0];
    float g0 = 0.f, g1 = 0.f, g2 = 0.f, g3 = 0.f;
#pragma unroll
    for (int i = 0; i < 16; ++i) {
      float4 w = wp[i];
      float4 a = s0p[i];
      g0 += w.x * a.x + w.y * a.y + w.z * a.z + w.w * a.w;
      float4 b = s1p[i];
      g1 += w.x * b.x + w.y * b.y + w.z * b.z + w.w * b.w;
      float4 c = s2p[i];
      g2 += w.x * c.x + w.y * c.y + w.z * c.z + w.w * c.w;
      float4 d = s3p[i];
      g3 += w.x * d.x + w.y * d.y + w.z * d.z + w.w * d.w;
    }
    G[((size_t)(bm0 + 0) * 12 + n) * 768 + p] = g0;
    G[((size_t)(bm0 + 1) * 12 + n) * 768 + p] = g1;
    G[((size_t)(bm0 + 2) * 12 + n) * 768 + p] = g2;
    G[((size_t)(bm0 + 3) * 12 + n) * 768 + p] = g3;
  }
}

// ---------------- F: out[t][p] = bp[p] + sum_n Z[n][t]*G[n][p] ----------------
__global__ __launch_bounds__(256) void k_out(const float* __restrict__ Z,
                                             const float* __restrict__ G,
                                             const float* __restrict__ bp,
                                             float* __restrict__ outp) {
  __shared__ __align__(16) float G_l[9216];
  __shared__ float Z_l[768];
  __shared__ __align__(16) float bp_l[768];
  const int bm = blockIdx.x;
  const int tbase = blockIdx.y * 64;
  const int tid = threadIdx.x;
  for (int i = tid; i < 9216; i += 256) G_l[i] = G[(size_t)bm * 9216 + i];
  for (int i = tid; i < 768; i += 256) {
    bp_l[i] = bp[i];
    Z_l[i] = Z[((size_t)bm * 12 + (i >> 6)) * 512 + tbase + (i & 63)];
  }
  __syncthreads();
  for (int it = 0; it < 48; ++it) {
    const int idx = it * 1024 + tid * 4;
    const int t = idx / 768;
    const int p = idx - t * 768;
    float4 o = *(const float4*)&bp_l[p];
#pragma unroll
    for (int n = 0; n < 12; ++n) {
      const float z = Z_l[n * 64 + t];
      const float4 g = *(const float4*)&G_l[n * 768 + p];
      o.x += z * g.x; o.y += z * g.y; o.z += z * g.z; o.w += z * g.w;
    }
    *(float4*)&outp[((size_t)bm * 512 + tbase + t) * 768 + p] = o;
  }
}

extern "C" void kernel_launch(void* const* d_in, const int* in_sizes, int n_in,
                              void* d_out, int out_size, void* d_ws, size_t ws_size,
                              hipStream_t stream) {
  const float* x    = (const float*)d_in[0];
  const float* mask = (const float*)d_in[1];
  const float* Wq   = (const float*)d_in[2];
  const float* bq   = (const float*)d_in[3];
  const float* Wk   = (const float*)d_in[4];
  const float* bk   = (const float*)d_in[5];
  const float* Wv   = (const float*)d_in[6];
  const float* bv   = (const float*)d_in[7];
  const float* Wp   = (const float*)d_in[8];
  const float* bp   = (const float*)d_in[9];
  float* outp = (float*)d_out;

  char* ws = (char*)d_ws;
  unsigned short* xbf  = (unsigned short*)(ws);                  // 100,663,296 B
  unsigned short* Wkbf = (unsigned short*)(ws + 100663296);      //   1,179,648
  unsigned short* Wqbf = (unsigned short*)(ws + 101842944);      //   1,179,648
  float* kd        = (float*)(ws + 103022592);                   //   3,145,728
  float* ksum_part = (float*)(ws + 106168320);                   //   1,572,864 ([128][4][768])
  float* xk_part   = (float*)(ws + 107741184);                   //  18,874,368
  float* Zb        = (float*)(ws + 126615552);                   //   3,145,728
  float* G         = (float*)(ws + 129761280);                   //   4,718,592
  // total ws: 134,479,872 B
  // q (bf16, 100,663,296 B) lives in d_out's first half until k_out overwrites.
  unsigned short* qbf = (unsigned short*)d_out;

  hipLaunchKernelGGL(k_cvt_all, dim3(25152), dim3(256), 0, stream,
                     x, Wk, Wq, xbf, Wkbf, Wqbf);
  hipLaunchKernelGGL(k_projqk, dim3(6, 512), dim3(512), 0, stream,
                     xbf, Wkbf, Wqbf, bk, bq, mask, kd, ksum_part, qbf);
  hipLaunchKernelGGL(k_xkz, dim3(1024), dim3(256), 0, stream,
                     xbf, kd, xk_part, qbf, ksum_part, Zb);
  hipLaunchKernelGGL(k_sg, dim3(12, 32), dim3(256), 0, stream,
                     ksum_part, xk_part, Wv, bv, Wp, G);
  hipLaunchKernelGGL(k_out, dim3(128, 8), dim3(256), 0, stream, Zb, G, bp, outp);
}